// Round 7
// baseline (1145.604 us; speedup 1.0000x reference)
//
#include <hip/hip_runtime.h>

// VQ-VAE VectorQuantizer for MI355X — single-pass bf16-MFMA screen + exact fp32 rescreen.
// inputs: d_in[0] = inputs [64, 64, 32, 32] fp32 (NCHW), d_in[1] = emb_w [512, 64] fp32
// output d_out (fp32): [loss(1), quantized NCHW (4194304), idx (65536)]
//
// Correctness: reference dist = fl(fl(sx+nk) - 2*dot) fp32, argmin first-index.
// Exact path (verified R2/R4/R5/R6): numpy-pairwise norms, sequential d-ascending
// FMA dot, v = fmaf(-2,dot,add_rn(sx,nk)), packed (bits<<32|k) CAS-min tiebreak.
// Screen: A_k = nk + MFMA(bf16(-2x), bf16(e)); |A_k - (nk-2dot)| <= delta where
// delta <= 2.01*2^-8*2*||x||*||e|| + 1e-5 <= 0.0157*sqrt(sx*emax2) + 1e-5
// (Cauchy-Schwarz; emax2 = max_k ||e_k||^2). Exact argmin k* obeys
// A_{k*} <= min_j A_j + 2*delta. MARGIN_pt = 0.033*sqrt(sx*emax2)+3e-5 >= 2*delta.
// Running-min queue: any k with A_k <= final_min + MARGIN is pushed at visit time
// (runv only decreases), or survives as a lane-best checked at merge. Queue
// overflow (expected fill ~150/512) falls back to full exact scan. Provably
// bit-identical to the exact path for ANY input.

#define D_    64
#define HW_   1024
#define N_    65536
#define K_    512
#define NDTOT 4194304
#define QCAP  512

typedef short v8s __attribute__((ext_vector_type(8)));
typedef float v4f __attribute__((ext_vector_type(4)));

__device__ float g_wsn[K_];     // ||e_k||^2 exact (numpy pairwise order)
__device__ float g_emax2;       // max_k ||e_k||^2
__device__ uint4 g_frag[4096];  // 64KB bf16 codebook, B-frag order: (t*2+s)*64+lane

__device__ __forceinline__ unsigned short bf16rn(float f) {
    unsigned int u = __float_as_uint(f);
    u += 0x7fffu + ((u >> 16) & 1u);
    return (unsigned short)(u >> 16);
}

// exact fp32 dist (reference arithmetic) + first-index-tiebreak min via LDS CAS
__device__ __forceinline__ void exact_min(const float* xcolp, const float* __restrict__ emb,
                                          int k, float nk, float sx,
                                          unsigned long long* keyp) {
    const float* e = emb + k * D_;
    float dot = 0.f;
#pragma unroll 8
    for (int d = 0; d < D_; ++d)
        dot = fmaf(xcolp[d * HW_], e[d], dot);     // sequential, d ascending
    float t1 = __fadd_rn(sx, nk);
    float v  = fmaf(-2.0f, dot, t1);               // == add_rn(t1, -2*dot)
    unsigned long long nv =
        (((unsigned long long)__float_as_uint(v)) << 32) | (unsigned int)k;
    unsigned long long old = *keyp;
    while (nv < old) {
        unsigned long long assumed = old;
        old = atomicCAS(keyp, assumed, nv);
        if (old == assumed) break;
    }
}

// ||e_k||^2 numpy-pairwise; also zeroes the loss accumulator
__global__ __launch_bounds__(256) void vq_prep_norm(const float* __restrict__ emb,
                                                    float* __restrict__ out) {
    int k = blockIdx.x * 256 + threadIdx.x;
    if (k == 0) out[0] = 0.f;
    if (k < K_) {
        const float* e = emb + k * D_;
        float r[8];
#pragma unroll
        for (int j = 0; j < 8; ++j) r[j] = __fmul_rn(e[j], e[j]);
#pragma unroll
        for (int i = 1; i < 8; ++i)
#pragma unroll
            for (int j = 0; j < 8; ++j)
                r[j] = __fadd_rn(r[j], __fmul_rn(e[i * 8 + j], e[i * 8 + j]));
        g_wsn[k] = __fadd_rn(__fadd_rn(__fadd_rn(r[0], r[1]), __fadd_rn(r[2], r[3])),
                             __fadd_rn(__fadd_rn(r[4], r[5]), __fadd_rn(r[6], r[7])));
    }
}

// codebook -> bf16 B-frags (hi only); block 0 also reduces emax2 (g_wsn from prev kernel)
__global__ __launch_bounds__(256) void vq_prep_frag(const float* __restrict__ emb) {
    const int tid = threadIdx.x;
    const int gid = blockIdx.x * 256 + tid;   // 0..4095 == (t*2+s)*64+lane
    const int t = gid >> 7, s = (gid >> 6) & 1, lane = gid & 63;
    const int c = lane & 15, q = lane >> 4;
    const float* e = emb + (t * 16 + c) * D_ + s * 32 + q * 8;
    unsigned int u[4];
#pragma unroll
    for (int jp = 0; jp < 4; ++jp)
        u[jp] = (unsigned int)bf16rn(e[jp * 2]) | ((unsigned int)bf16rn(e[jp * 2 + 1]) << 16);
    g_frag[gid] = make_uint4(u[0], u[1], u[2], u[3]);

    if (blockIdx.x == 0 && tid < 64) {
        float m = 0.f;
#pragma unroll
        for (int i = 0; i < 8; ++i) m = fmaxf(m, g_wsn[tid * 8 + i]);
#pragma unroll
        for (int off = 32; off > 0; off >>= 1) m = fmaxf(m, __shfl_xor(m, off, 64));
        if (tid == 0) g_emax2 = m;
    }
}

__global__ __launch_bounds__(256, 2) void vq_main_kernel(const float* __restrict__ inp,
                                                         const float* __restrict__ emb,
                                                         float* __restrict__ out) {
    __shared__ __align__(16) char smem[71700];
    float* ldsx = (float*)smem;                         // phase A: xT[64][128] (32KB)
    v8s*   ldsB = (v8s*)smem;                           // phase B: 64KB frag codebook
    float* ldsn = (float*)(smem + 65536);               // ||e_k||^2 [512]
    float* sxs  = (float*)(smem + 67584);               // ||x_p||^2 [128]
    unsigned long long* key_ = (unsigned long long*)(smem + 68096);  // [128]
    int*   queue_ = (int*)(smem + 69120);               // [QCAP]
    int*   qn_    = (int*)(smem + 71168);
    int*   ai_    = (int*)(smem + 71172);               // [128]
    float* partial = (float*)(smem + 71684);            // [4]

    const int tid = threadIdx.x;
    const int lane = tid & 63;
    const int w = tid >> 6;
    const int c = lane & 15, q = lane >> 4;

    const int n0 = blockIdx.x * 128;
    const int b = n0 >> 10;
    const int hw0 = n0 & 1023;
    const float* xg = inp + b * (D_ * HW_) + hw0;

    // ---- stage xT[d][p] (coalesced) + norms to LDS ----
#pragma unroll
    for (int i = 0; i < 8; ++i) {
        int idx = i * 256 + tid;
        int d = idx >> 5, pq = idx & 31;
        *(float4*)(ldsx + d * 128 + pq * 4) = *(const float4*)(xg + d * HW_ + pq * 4);
    }
    ldsn[tid] = g_wsn[tid];
    ldsn[tid + 256] = g_wsn[tid + 256];
    const float em2 = g_emax2;
    __syncthreads();

    // ---- sxs[p] = ||x_p||^2, numpy pairwise (tid<128) ----
    if (tid < 128) {
        float r[8];
#pragma unroll
        for (int j = 0; j < 8; ++j) { float v = ldsx[j * 128 + tid]; r[j] = __fmul_rn(v, v); }
#pragma unroll
        for (int i = 1; i < 8; ++i)
#pragma unroll
            for (int j = 0; j < 8; ++j) {
                float v = ldsx[(i * 8 + j) * 128 + tid];
                r[j] = __fadd_rn(r[j], __fmul_rn(v, v));
            }
        sxs[tid] = __fadd_rn(__fadd_rn(__fadd_rn(r[0], r[1]), __fadd_rn(r[2], r[3])),
                             __fadd_rn(__fadd_rn(r[4], r[5]), __fadd_rn(r[6], r[7])));
    }

    // ---- A-frags: y = -2x in bf16 (hi only); wave w owns points w*32..w*32+31 ----
    v8s ah[2][2];
#pragma unroll
    for (int T = 0; T < 2; ++T)
#pragma unroll
        for (int s = 0; s < 2; ++s) {
            int pt = w * 32 + T * 16 + c;
#pragma unroll
            for (int j = 0; j < 8; ++j) {
                float x = ldsx[(s * 32 + q * 8 + j) * 128 + pt];
                ah[T][s][j] = (short)bf16rn(-2.0f * x);
            }
        }
    __syncthreads();   // ldsx reads done; sxs visible

    // ---- stage whole bf16 codebook into LDS (overwrites ldsx) ----
    {
        uint4* dst = (uint4*)smem;
#pragma unroll
        for (int i = 0; i < 16; ++i) dst[i * 256 + tid] = g_frag[i * 256 + tid];
    }
    // per-point margins
    float mg[2][4];
    int pts[2][4];
#pragma unroll
    for (int T = 0; T < 2; ++T)
#pragma unroll
        for (int r = 0; r < 4; ++r) {
            int pt = w * 32 + T * 16 + q * 4 + r;
            pts[T][r] = pt;
            mg[T][r] = 0.033f * sqrtf(sxs[pt] * em2) + 3e-5f;
        }
    if (tid < 128) key_[tid] = 0xFFFFFFFFFFFFFFFFULL;
    if (tid == 0) *qn_ = 0;
    __syncthreads();

    // ---- single-pass screen: 32 iterations, no barriers ----
    float runv[2][4]; int runi[2][4];
#pragma unroll
    for (int T = 0; T < 2; ++T)
#pragma unroll
        for (int r = 0; r < 4; ++r) { runv[T][r] = 3.4e38f; runi[T][r] = 0; }

#pragma unroll 4
    for (int t = 0; t < 32; ++t) {
        float nk = ldsn[t * 16 + c];
        v8s bh0 = ldsB[(t * 2 + 0) * 64 + lane];
        v8s bh1 = ldsB[(t * 2 + 1) * 64 + lane];
        v4f a0 = {nk, nk, nk, nk}, a1 = {nk, nk, nk, nk};
        a0 = __builtin_amdgcn_mfma_f32_16x16x32_bf16(ah[0][0], bh0, a0, 0, 0, 0);
        a0 = __builtin_amdgcn_mfma_f32_16x16x32_bf16(ah[0][1], bh1, a0, 0, 0, 0);
        a1 = __builtin_amdgcn_mfma_f32_16x16x32_bf16(ah[1][0], bh0, a1, 0, 0, 0);
        a1 = __builtin_amdgcn_mfma_f32_16x16x32_bf16(ah[1][1], bh1, a1, 0, 0, 0);
        const int kl = t * 16 + c;
#pragma unroll
        for (int r = 0; r < 4; ++r) {
            float v0 = a0[r];
            if (v0 < runv[0][r]) {
                if (runv[0][r] <= v0 + mg[0][r]) {
                    int s_ = atomicAdd(qn_, 1);
                    if (s_ < QCAP) queue_[s_] = (pts[0][r] << 9) | runi[0][r];
                }
                runv[0][r] = v0; runi[0][r] = kl;
            } else if (v0 <= runv[0][r] + mg[0][r]) {
                int s_ = atomicAdd(qn_, 1);
                if (s_ < QCAP) queue_[s_] = (pts[0][r] << 9) | kl;
            }
            float v1 = a1[r];
            if (v1 < runv[1][r]) {
                if (runv[1][r] <= v1 + mg[1][r]) {
                    int s_ = atomicAdd(qn_, 1);
                    if (s_ < QCAP) queue_[s_] = (pts[1][r] << 9) | runi[1][r];
                }
                runv[1][r] = v1; runi[1][r] = kl;
            } else if (v1 <= runv[1][r] + mg[1][r]) {
                int s_ = atomicAdd(qn_, 1);
                if (s_ < QCAP) queue_[s_] = (pts[1][r] << 9) | kl;
            }
        }
    }

    // ---- merge 16 lanes per point; push lane-bests within margin ----
#pragma unroll
    for (int T = 0; T < 2; ++T)
#pragma unroll
        for (int r = 0; r < 4; ++r) {
            float v = runv[T][r]; int i = runi[T][r];
            float bv = v; int bi = i;
#pragma unroll
            for (int off = 1; off < 16; off <<= 1) {
                float ov = __shfl_xor(bv, off, 64);
                int   oi = __shfl_xor(bi, off, 64);
                if (ov < bv || (ov == bv && oi < bi)) { bv = ov; bi = oi; }
            }
            if (c == 0) ai_[pts[T][r]] = bi;
            if (i != bi && v <= bv + mg[T][r]) {
                int s_ = atomicAdd(qn_, 1);
                if (s_ < QCAP) queue_[s_] = (pts[T][r] << 9) | i;
            }
        }
    __syncthreads();

    // ---- exact phase ----
    int qn_v = *qn_;
    if (qn_v > QCAP) {
        // provable fallback (never expected): full exact scan
        if (tid < 128)
            for (int k = 0; k < K_; ++k)
                exact_min(xg + tid, emb, k, ldsn[k], sxs[tid], &key_[tid]);
    } else {
        if (tid < 128) {
            int bk = ai_[tid];
            exact_min(xg + tid, emb, bk, ldsn[bk], sxs[tid], &key_[tid]);
        }
        for (int i = tid; i < qn_v; i += 256) {
            int ent = queue_[i];
            int pt = ent >> 9, k = ent & 511;
            exact_min(xg + pt, emb, k, ldsn[k], sxs[pt], &key_[pt]);
        }
    }
    __syncthreads();

    // ---- idx output ----
    if (tid < 128) {
        unsigned int kf = (unsigned int)(key_[tid] & 0xffffffffULL);
        ai_[tid] = (int)kf;
        out[1 + NDTOT + n0 + tid] = (float)kf;
    }
    __syncthreads();

    // ---- quantized output (NCHW) + loss ----
    const int h = tid >> 7, p = tid & 127;
    const int idx = ai_[p];
    const float4* erow = (const float4*)(emb + idx * D_) + h * 8;
    const float* xcol = xg + p;
    float* ob = out + 1 + b * (D_ * HW_) + hw0 + p;
    float local = 0.f;
#pragma unroll
    for (int j = 0; j < 8; ++j) {
        float4 e4 = erow[j];
        int d0 = h * 32 + j * 4;
        float ev[4] = {e4.x, e4.y, e4.z, e4.w};
#pragma unroll
        for (int cc = 0; cc < 4; ++cc) {
            float xv = xcol[(d0 + cc) * HW_];
            float df = ev[cc] - xv;
            local = fmaf(df, df, local);
            ob[(d0 + cc) * HW_] = ev[cc];
        }
    }
#pragma unroll
    for (int off = 32; off > 0; off >>= 1)
        local += __shfl_down(local, off, 64);
    if ((tid & 63) == 0) partial[tid >> 6] = local;
    __syncthreads();
    if (tid == 0) {
        float t = partial[0] + partial[1] + partial[2] + partial[3];
        atomicAdd(out, t * (1.25f / (float)NDTOT));   // loss = 1.25*mean((q-x)^2)
    }
}

extern "C" void kernel_launch(void* const* d_in, const int* in_sizes, int n_in,
                              void* d_out, int out_size, void* d_ws, size_t ws_size,
                              hipStream_t stream) {
    const float* inp = (const float*)d_in[0];
    const float* emb = (const float*)d_in[1];
    float* out = (float*)d_out;

    vq_prep_norm<<<2, 256, 0, stream>>>(emb, out);
    vq_prep_frag<<<16, 256, 0, stream>>>(emb);
    vq_main_kernel<<<N_ / 128, 256, 0, stream>>>(inp, emb, out);
}